// Round 4
// baseline (77.928 us; speedup 1.0000x reference)
//
#include <hip/hip_runtime.h>
#include <cfloat>

// Problem constants (from reference): B=8, C=2, H=256, W=256
#define BB 8
#define CC 2
#define HH 256
#define WW 256

static constexpr float EDT_INF = 1e4f;          // matches reference INF
static constexpr int   NPIX    = BB * HH * WW;  // 524288
static constexpr double FXS    = 16777216.0;    // 2^24 fixed-point scale

// ---------------------------------------------------------------------------
// K0: init scratch scalars (tmin, fixed-point accumulator, completion counter)
__global__ void k_init(int* tmin, unsigned long long* acc, unsigned int* count) {
    *tmin = 0x7fffffff;
    *acc = 0ULL;
    *count = 0u;
}

// K1: global min of target (int), vectorized, deterministic atomicMin
__global__ void k_tmin(const int* __restrict__ target, int* __restrict__ tmin) {
    // 64 blocks x 256 threads x 8 int4 = 524288 ints, exact cover
    const int4* t4 = (const int4*)target;
    int local = 0x7fffffff;
    int idx = blockIdx.x * blockDim.x + threadIdx.x;
#pragma unroll
    for (int r = 0; r < 8; ++r) {
        int4 v = t4[idx + r * 64 * 256];
        local = min(local, min(min(v.x, v.y), min(v.z, v.w)));
    }
    __shared__ int s[256];
    s[threadIdx.x] = local;
    __syncthreads();
    for (int st = 128; st > 0; st >>= 1) {
        if (threadIdx.x < st) s[threadIdx.x] = min(s[threadIdx.x], s[threadIdx.x + st]);
        __syncthreads();
    }
    if (threadIdx.x == 0) atomicMin(tmin, s[0]);
}

// ---------------------------------------------------------------------------
// K2: build per-column 256-bit masks for pc (= argmax(preds)) and gt (= target
// with 255->tmin, >0). One block per (b,w) column, one thread per row; ballot.
// Layout: mask[((b*4)+k)*W + w], k = 64-row word index.
__global__ void k_masks(const float* __restrict__ preds,
                        const int*   __restrict__ target,
                        const int*   __restrict__ tminp,
                        unsigned long long* __restrict__ mPC,
                        unsigned long long* __restrict__ mGT) {
    const int blk = blockIdx.x;            // b*W + w
    const int b = blk >> 8, w = blk & 255;
    const int i = threadIdx.x;             // row
    const int tmin = *tminp;

    float a0 = preds[((size_t)b * CC + 0) * HH * WW + (size_t)i * WW + w];
    float a1 = preds[((size_t)b * CC + 1) * HH * WW + (size_t)i * WW + w];
    bool pc = (a1 > a0);                   // argmax over C=2, ties -> class 0
    int tv = target[(size_t)b * HH * WW + (size_t)i * WW + w];
    if (tv == 255) tv = tmin;
    bool gt = (tv > 0);

    unsigned long long bp = __ballot(pc);
    unsigned long long bg = __ballot(gt);
    if ((i & 63) == 0) {
        int k = i >> 6;
        mPC[((size_t)b * 4 + k) * WW + w] = bp;
        mGT[((size_t)b * 4 + k) * WW + w] = bg;
    }
}

// ---------------------------------------------------------------------------
// Closed-form vertical scan value from a 256-bit column mask.
// Reproduces exactly (in f32): fwd scan d = m ? carry+1 : 0, carry init 1e4,
// top->down; bwd bottom->up; g = min(fwd,bwd); returns g*g.
__device__ __forceinline__ float g2_of(const unsigned long long* m, int i, bool set) {
    if (!set) return 0.0f;
    float fwd = EDT_INF + (float)(i + 1);     // run reaches top
    {
        int k = i - 1;
        if (k >= 0) {
            int w = k >> 6;
            unsigned long long t = ~m[w] & (~0ULL >> (63 - (k & 63)));
            for (;;) {
                if (t) { int j = (w << 6) + 63 - __builtin_clzll(t); fwd = (float)(i - j); break; }
                if (--w < 0) break;
                t = ~m[w];
            }
        }
    }
    float bwd = EDT_INF + (float)(HH - i);    // run reaches bottom
    {
        int k = i + 1;
        if (k < HH) {
            int w = k >> 6;
            unsigned long long t = ~m[w] & (~0ULL << (k & 63));
            for (;;) {
                if (t) { int j = (w << 6) + __builtin_ctzll(t); bwd = (float)(j - i); break; }
                if (++w >= 4) break;
                t = ~m[w];
            }
        }
    }
    float g = fminf(fwd, bwd);
    return g * g;
}

// ---------------------------------------------------------------------------
// K3: fused per-row kernel. Loads the image's column masks (coalesced),
// recomputes all 4 vertical g^2 values per pixel, does both horizontal
// early-exit searches, the final elementwise math, a deterministic block
// reduction, fixed-point global accumulation, and last-block finalize.
__global__ void k_fused(const int* __restrict__ target,
                        const int* __restrict__ tminp,
                        const unsigned long long* __restrict__ mPC,
                        const unsigned long long* __restrict__ mGT,
                        unsigned long long* __restrict__ acc,
                        unsigned int* __restrict__ count,
                        float* __restrict__ out) {
    const int row = blockIdx.x;            // 0 .. B*H-1
    const int b = row >> 8, i = row & 255;
    const int j = threadIdx.x;             // column

    unsigned long long wp[4], wg[4], np[4], ng[4];
#pragma unroll
    for (int k = 0; k < 4; ++k) {
        wp[k] = mPC[((size_t)b * 4 + k) * WW + j];   // coalesced stride-8B
        wg[k] = mGT[((size_t)b * 4 + k) * WW + j];
        np[k] = ~wp[k]; ng[k] = ~wg[k];
    }
    bool pc = (wp[i >> 6] >> (i & 63)) & 1ULL;
    bool gt = (wg[i >> 6] >> (i & 63)) & 1ULL;

    __shared__ float s_pm[WW], s_pn[WW], s_gm[WW], s_gn[WW];
    s_pm[j] = g2_of(wp, i, pc);
    s_pn[j] = g2_of(np, i, !pc);
    s_gm[j] = g2_of(wg, i, gt);
    s_gn[j] = g2_of(ng, i, !gt);
    __syncthreads();

    // --- pc distance (the edt term that is nonzero at this pixel) ---
    const float* rv = pc ? s_pm : s_pn;
    float mn = rv[j];
    for (int d = 1; d < WW; ++d) {
        float dd = (float)(d * d);
        if (__all(dd >= mn)) break;
        int kl = j - d, kr = j + d;
        if (kl >= 0) mn = fminf(mn, dd + rv[kl]);
        if (kr < WW) mn = fminf(mn, dd + rv[kr]);
    }
    float pd = sqrtf(mn);

    // --- gt distance ---
    const float* rw = gt ? s_gm : s_gn;
    float mg = rw[j];
    for (int d = 1; d < WW; ++d) {
        float dd = (float)(d * d);
        if (__all(dd >= mg)) break;
        int kl = j - d, kr = j + d;
        if (kl >= 0) mg = fminf(mg, dd + rw[kl]);
        if (kr < WW) mg = fminf(mg, dd + rw[kr]);
    }
    float gd = sqrtf(mg);

    // --- final elementwise math (mirrors reference op order) ---
    int tv = target[(size_t)row * WW + j];
    if (tv == 255) tv = *tminp;
    float gtv = (float)tv;
    float pcv = pc ? 1.0f : 0.0f;
    float err  = fabsf(gtv - pcv);
    float dist = sqrtf(pd * pd + gd * gd);
    float mult = sqrtf(err * dist + 1e-9f);

    __shared__ float red[WW];
    red[j] = mult;
    __syncthreads();
    for (int st = 128; st > 0; st >>= 1) {
        if (j < st) red[j] += red[j + st];
        __syncthreads();
    }
    if (j == 0) {
        // deterministic: fixed-point integer accumulation (assoc. int adds)
        unsigned long long q = (unsigned long long)llrint((double)red[0] * FXS);
        atomicAdd(acc, q);
        __threadfence();
        unsigned int old = atomicAdd(count, 1u);
        if (old == (unsigned int)(BB * HH - 1)) {
            unsigned long long tot = atomicAdd(acc, 0ULL);  // coherent read
            out[0] = (float)((double)tot * (1.0 / FXS) * (1.0 / (double)NPIX));
        }
    }
}

// ---------------------------------------------------------------------------
extern "C" void kernel_launch(void* const* d_in, const int* in_sizes, int n_in,
                              void* d_out, int out_size, void* d_ws, size_t ws_size,
                              hipStream_t stream) {
    const float* preds  = (const float*)d_in[0];
    const int*   target = (const int*)d_in[1];
    float* out = (float*)d_out;

    // ws layout: masks (2 x 64KB), then scalars
    unsigned long long* mPC = (unsigned long long*)d_ws;            // 8*4*256 = 8192 ULL
    unsigned long long* mGT = mPC + (size_t)BB * 4 * WW;            // 8192 ULL
    unsigned long long* acc = mGT + (size_t)BB * 4 * WW;            // 1 ULL
    int*          tmin  = (int*)(acc + 1);
    unsigned int* count = (unsigned int*)(tmin + 1);

    k_init<<<1, 1, 0, stream>>>(tmin, acc, count);
    k_tmin<<<64, 256, 0, stream>>>(target, tmin);
    k_masks<<<BB * WW, HH, 0, stream>>>(preds, target, tmin, mPC, mGT);
    k_fused<<<BB * HH, WW, 0, stream>>>(target, tmin, mPC, mGT, acc, count, out);
}

// Round 5
// 37.299 us; speedup vs baseline: 2.0893x; 2.0893x over previous
//
#include <hip/hip_runtime.h>
#include <cfloat>

// Problem constants (from reference): B=8, C=2, H=256, W=256
#define BB 8
#define CC 2
#define HH 256
#define WW 256

static constexpr float EDT_INF = 1e4f;          // matches reference INF
static constexpr int   NPIX    = BB * HH * WW;  // 524288

// ---------------------------------------------------------------------------
// K0: init tmin slot
__global__ void k_init(int* tmin) { *tmin = 0x7fffffff; }

// K1: global min of target (int), vectorized, deterministic atomicMin
// (only 64 atomics to one address -> negligible contention)
__global__ void k_tmin(const int* __restrict__ target, int* __restrict__ tmin) {
    // 64 blocks x 256 threads x 8 int4 = 524288 ints, exact cover
    const int4* t4 = (const int4*)target;
    int local = 0x7fffffff;
    int idx = blockIdx.x * blockDim.x + threadIdx.x;
#pragma unroll
    for (int r = 0; r < 8; ++r) {
        int4 v = t4[idx + r * 64 * 256];
        local = min(local, min(min(v.x, v.y), min(v.z, v.w)));
    }
    __shared__ int s[256];
    s[threadIdx.x] = local;
    __syncthreads();
    for (int st = 128; st > 0; st >>= 1) {
        if (threadIdx.x < st) s[threadIdx.x] = min(s[threadIdx.x], s[threadIdx.x + st]);
        __syncthreads();
    }
    if (threadIdx.x == 0) atomicMin(tmin, s[0]);
}

// ---------------------------------------------------------------------------
// K2: build per-column 256-bit masks for pc (= argmax(preds)) and gt (= target
// with 255->tmin, >0). One block per (b,w) column, one thread per row; ballot.
// Layout: mask[((b*4)+k)*W + w], k = 64-row word index.
__global__ void k_masks(const float* __restrict__ preds,
                        const int*   __restrict__ target,
                        const int*   __restrict__ tminp,
                        unsigned long long* __restrict__ mPC,
                        unsigned long long* __restrict__ mGT) {
    const int blk = blockIdx.x;            // b*W + w
    const int b = blk >> 8, w = blk & 255;
    const int i = threadIdx.x;             // row
    const int tmin = *tminp;

    float a0 = preds[((size_t)b * CC + 0) * HH * WW + (size_t)i * WW + w];
    float a1 = preds[((size_t)b * CC + 1) * HH * WW + (size_t)i * WW + w];
    bool pc = (a1 > a0);                   // argmax over C=2, ties -> class 0
    int tv = target[(size_t)b * HH * WW + (size_t)i * WW + w];
    if (tv == 255) tv = tmin;
    bool gt = (tv > 0);

    unsigned long long bp = __ballot(pc);
    unsigned long long bg = __ballot(gt);
    if ((i & 63) == 0) {
        int k = i >> 6;
        mPC[((size_t)b * 4 + k) * WW + w] = bp;
        mGT[((size_t)b * 4 + k) * WW + w] = bg;
    }
}

// ---------------------------------------------------------------------------
// Closed-form vertical scan value from a 256-bit column mask.
// Reproduces exactly (in f32): fwd scan d = m ? carry+1 : 0, carry init 1e4,
// top->down; bwd bottom->up; g = min(fwd,bwd); returns g*g.
__device__ __forceinline__ float g2_of(const unsigned long long* m, int i, bool set) {
    if (!set) return 0.0f;
    float fwd = EDT_INF + (float)(i + 1);     // run reaches top
    {
        int k = i - 1;
        if (k >= 0) {
            int w = k >> 6;
            unsigned long long t = ~m[w] & (~0ULL >> (63 - (k & 63)));
            for (;;) {
                if (t) { int j = (w << 6) + 63 - __builtin_clzll(t); fwd = (float)(i - j); break; }
                if (--w < 0) break;
                t = ~m[w];
            }
        }
    }
    float bwd = EDT_INF + (float)(HH - i);    // run reaches bottom
    {
        int k = i + 1;
        if (k < HH) {
            int w = k >> 6;
            unsigned long long t = ~m[w] & (~0ULL << (k & 63));
            for (;;) {
                if (t) { int j = (w << 6) + __builtin_ctzll(t); bwd = (float)(j - i); break; }
                if (++w >= 4) break;
                t = ~m[w];
            }
        }
    }
    float g = fminf(fwd, bwd);
    return g * g;
}

// ---------------------------------------------------------------------------
// K3: fused per-row kernel. Loads the image's column masks (coalesced),
// recomputes all 4 vertical g^2 values per pixel, does both horizontal
// early-exit searches, the final elementwise math, and a deterministic
// in-block reduction to partials[row]. NO global atomics (R4's 58us lesson:
// 2048 same-address device atomics serialize across XCDs).
__global__ void k_fused(const int* __restrict__ target,
                        const int* __restrict__ tminp,
                        const unsigned long long* __restrict__ mPC,
                        const unsigned long long* __restrict__ mGT,
                        float* __restrict__ partials) {
    const int row = blockIdx.x;            // 0 .. B*H-1
    const int b = row >> 8, i = row & 255;
    const int j = threadIdx.x;             // column

    unsigned long long wp[4], wg[4], np[4], ng[4];
#pragma unroll
    for (int k = 0; k < 4; ++k) {
        wp[k] = mPC[((size_t)b * 4 + k) * WW + j];   // coalesced stride-8B
        wg[k] = mGT[((size_t)b * 4 + k) * WW + j];
        np[k] = ~wp[k]; ng[k] = ~wg[k];
    }
    bool pc = (wp[i >> 6] >> (i & 63)) & 1ULL;
    bool gt = (wg[i >> 6] >> (i & 63)) & 1ULL;

    __shared__ float s_pm[WW], s_pn[WW], s_gm[WW], s_gn[WW];
    s_pm[j] = g2_of(wp, i, pc);
    s_pn[j] = g2_of(np, i, !pc);
    s_gm[j] = g2_of(wg, i, gt);
    s_gn[j] = g2_of(ng, i, !gt);
    __syncthreads();

    // --- pc distance (the edt term that is nonzero at this pixel) ---
    const float* rv = pc ? s_pm : s_pn;
    float mn = rv[j];
    for (int d = 1; d < WW; ++d) {
        float dd = (float)(d * d);
        if (__all(dd >= mn)) break;
        int kl = j - d, kr = j + d;
        if (kl >= 0) mn = fminf(mn, dd + rv[kl]);
        if (kr < WW) mn = fminf(mn, dd + rv[kr]);
    }
    float pd = sqrtf(mn);

    // --- gt distance ---
    const float* rw = gt ? s_gm : s_gn;
    float mg = rw[j];
    for (int d = 1; d < WW; ++d) {
        float dd = (float)(d * d);
        if (__all(dd >= mg)) break;
        int kl = j - d, kr = j + d;
        if (kl >= 0) mg = fminf(mg, dd + rw[kl]);
        if (kr < WW) mg = fminf(mg, dd + rw[kr]);
    }
    float gd = sqrtf(mg);

    // --- final elementwise math (mirrors reference op order) ---
    int tv = target[(size_t)row * WW + j];
    if (tv == 255) tv = *tminp;
    float gtv = (float)tv;
    float pcv = pc ? 1.0f : 0.0f;
    float err  = fabsf(gtv - pcv);
    float dist = sqrtf(pd * pd + gd * gd);
    float mult = sqrtf(err * dist + 1e-9f);

    __shared__ float red[WW];
    red[j] = mult;
    __syncthreads();
    for (int st = 128; st > 0; st >>= 1) {
        if (j < st) red[j] += red[j + st];
        __syncthreads();
    }
    if (j == 0) partials[row] = red[0];
}

// ---------------------------------------------------------------------------
// K4: final deterministic reduction of B*H partials -> mean (fixed order)
__global__ void k_final(const float* __restrict__ partials, float* __restrict__ out) {
    __shared__ float s[256];
    float acc = 0.0f;
    for (int k = threadIdx.x; k < BB * HH; k += 256) acc += partials[k];
    s[threadIdx.x] = acc;
    __syncthreads();
    for (int st = 128; st > 0; st >>= 1) {
        if (threadIdx.x < st) s[threadIdx.x] += s[threadIdx.x + st];
        __syncthreads();
    }
    if (threadIdx.x == 0) out[0] = s[0] * (1.0f / (float)NPIX);  // /2^19: exact
}

// ---------------------------------------------------------------------------
extern "C" void kernel_launch(void* const* d_in, const int* in_sizes, int n_in,
                              void* d_out, int out_size, void* d_ws, size_t ws_size,
                              hipStream_t stream) {
    const float* preds  = (const float*)d_in[0];
    const int*   target = (const int*)d_in[1];
    float* out = (float*)d_out;

    // ws layout: masks (2 x 64KB), partials, tmin
    unsigned long long* mPC = (unsigned long long*)d_ws;            // 8*4*256 ULL
    unsigned long long* mGT = mPC + (size_t)BB * 4 * WW;            // 8*4*256 ULL
    float* partials = (float*)(mGT + (size_t)BB * 4 * WW);          // B*H floats
    int*   tmin     = (int*)(partials + BB * HH);

    k_init<<<1, 1, 0, stream>>>(tmin);
    k_tmin<<<64, 256, 0, stream>>>(target, tmin);
    k_masks<<<BB * WW, HH, 0, stream>>>(preds, target, tmin, mPC, mGT);
    k_fused<<<BB * HH, WW, 0, stream>>>(target, tmin, mPC, mGT, partials);
    k_final<<<1, 256, 0, stream>>>(partials, out);
}

// Round 6
// 25.015 us; speedup vs baseline: 3.1153x; 1.4911x over previous
//
#include <hip/hip_runtime.h>
#include <cfloat>

// Problem constants (from reference): B=8, C=2, H=256, W=256
#define BB 8
#define CC 2
#define HH 256
#define WW 256

typedef unsigned long long ull;

static constexpr float EDT_INF = 1e4f;          // matches reference INF
static constexpr int   NPIX    = BB * HH * WW;  // 524288

// ---------------------------------------------------------------------------
// 1D nearest-zero-bit distance^2 from a 256-bit mask, reproducing the
// reference f32 scan exactly: fwd d = m ? carry+1 : 0 (carry init 1e4),
// bwd symmetric, g = min(fwd,bwd), return g*g. pos = bit index.
__device__ __forceinline__ float g2_of(const ull* m, int pos, bool set) {
    if (!set) return 0.0f;
    float fwd = EDT_INF + (float)(pos + 1);   // run reaches low edge
    {
        int k = pos - 1;
        if (k >= 0) {
            int w = k >> 6;
            ull t = ~m[w] & (~0ULL >> (63 - (k & 63)));
            for (;;) {
                if (t) { int j = (w << 6) + 63 - __builtin_clzll(t); fwd = (float)(pos - j); break; }
                if (--w < 0) break;
                t = ~m[w];
            }
        }
    }
    float bwd = EDT_INF + (float)(256 - pos); // run reaches high edge
    {
        int k = pos + 1;
        if (k < 256) {
            int w = k >> 6;
            ull t = ~m[w] & (~0ULL << (k & 63));
            for (;;) {
                if (t) { int j = (w << 6) + __builtin_ctzll(t); bwd = (float)(j - pos); break; }
                if (++w >= 4) break;
                t = ~m[w];
            }
        }
    }
    float g = fminf(fwd, bwd);
    return g * g;
}

// ---------------------------------------------------------------------------
// K1: build ROW masks (coalesced: lanes across w) + per-block tmin partials.
// Grid: 256 blocks = b(8) x 8-row-group(32); 256 threads = 4 waves, wave wv
// covers w in [64*wv, 64*wv+64). Masks stored as mask[(b*256+i)*4 + wv].
// Three masks: pc (argmax preds), gt0 (tv>0), g255 (tv==255); the actual gt
// mask is fixed up in k_fused once tmin is known.
__global__ void k_masks(const float* __restrict__ preds,
                        const int*   __restrict__ target,
                        ull* __restrict__ mPC, ull* __restrict__ mGT0,
                        ull* __restrict__ mG255, int* __restrict__ tminPart) {
    const int blk = blockIdx.x;
    const int b  = blk >> 5;               // image
    const int ig = blk & 31;               // 8-row group
    const int wv = threadIdx.x >> 6;       // word index 0..3
    const int ln = threadIdx.x & 63;
    const int w  = (wv << 6) | ln;

    int tmin = 0x7fffffff;
#pragma unroll
    for (int r = 0; r < 8; ++r) {
        int i = ig * 8 + r;
        float a0 = preds[((size_t)b * CC + 0) * HH * WW + (size_t)i * WW + w];
        float a1 = preds[((size_t)b * CC + 1) * HH * WW + (size_t)i * WW + w];
        bool pc = (a1 > a0);               // argmax over C=2, ties -> class 0
        int tv = target[((size_t)b * HH + i) * WW + w];
        tmin = min(tmin, tv);
        ull bp = __ballot(pc);
        ull b0 = __ballot(tv > 0);
        ull b2 = __ballot(tv == 255);
        if (ln == 0) {
            size_t midx = ((size_t)b * HH + i) * 4 + wv;
            mPC[midx] = bp; mGT0[midx] = b0; mG255[midx] = b2;
        }
    }
    __shared__ int s[256];
    s[threadIdx.x] = tmin;
    __syncthreads();
    for (int st = 128; st > 0; st >>= 1) {
        if (threadIdx.x < st) s[threadIdx.x] = min(s[threadIdx.x], s[threadIdx.x + st]);
        __syncthreads();
    }
    if (threadIdx.x == 0) tminPart[blk] = s[0];
}

// ---------------------------------------------------------------------------
// K2: fused per-COLUMN kernel (axis-swapped separable EDT: horizontal 1D
// distance from row masks, then vertical min_k h2[k] + (i-k)^2 — exact EDT,
// identical values whenever the polarity has >=1 zero pixel in the image).
// One block per (b,j); thread i = row. No global atomics.
__global__ void k_fused(const int* __restrict__ target,
                        const ull* __restrict__ mPC,
                        const ull* __restrict__ mGT0,
                        const ull* __restrict__ mG255,
                        const int* __restrict__ tminPart,
                        float* __restrict__ partials) {
    const int blk = blockIdx.x;            // b*256 + j
    const int b = blk >> 8, j = blk & 255;
    const int i = threadIdx.x;             // row

    // tmin = min of the 256 block partials (one load per thread)
    __shared__ int stm[256];
    stm[i] = tminPart[i];
    __syncthreads();
    for (int st = 128; st > 0; st >>= 1) {
        if (i < st) stm[i] = min(stm[i], stm[i + st]);
        __syncthreads();
    }
    const int tmin = stm[0];
    const bool allpos = (tmin > 0);

    // row i's masks: 4 consecutive ULLs each -> coalesced dwordx4 loads
    ull wp[4], wg[4], np[4], ng[4];
    {
        const ull* pP = mPC   + ((size_t)b * HH + i) * 4;
        const ull* p0 = mGT0  + ((size_t)b * HH + i) * 4;
        const ull* p2 = mG255 + ((size_t)b * HH + i) * 4;
#pragma unroll
        for (int k = 0; k < 4; ++k) {
            wp[k] = pP[k];
            ull g = p0[k];
            if (!allpos) g &= ~p2[k];      // 255 -> tmin==0 -> not >0
            wg[k] = g;
            np[k] = ~wp[k]; ng[k] = ~wg[k];
        }
    }
    bool pc = (wp[j >> 6] >> (j & 63)) & 1ULL;
    bool gt = (wg[j >> 6] >> (j & 63)) & 1ULL;

    // stage the four horizontal distance^2 rows (value at (i,j) per polarity)
    __shared__ float s_pm[HH], s_pn[HH], s_gm[HH], s_gn[HH];
    s_pm[i] = g2_of(wp, j, pc);
    s_pn[i] = g2_of(np, j, !pc);
    s_gm[i] = g2_of(wg, j, gt);
    s_gn[i] = g2_of(ng, j, !gt);
    __syncthreads();

    // --- pc distance: vertical min with exact early exit ---
    const float* rv = pc ? s_pm : s_pn;
    float mn = rv[i];
    for (int d = 1; d < HH; ++d) {
        float dd = (float)(d * d);
        if (__all(dd >= mn)) break;
        int kl = i - d, kr = i + d;
        if (kl >= 0) mn = fminf(mn, dd + rv[kl]);
        if (kr < HH) mn = fminf(mn, dd + rv[kr]);
    }
    float pd = sqrtf(mn);

    // --- gt distance ---
    const float* rw = gt ? s_gm : s_gn;
    float mg = rw[i];
    for (int d = 1; d < HH; ++d) {
        float dd = (float)(d * d);
        if (__all(dd >= mg)) break;
        int kl = i - d, kr = i + d;
        if (kl >= 0) mg = fminf(mg, dd + rw[kl]);
        if (kr < HH) mg = fminf(mg, dd + rw[kr]);
    }
    float gd = sqrtf(mg);

    // --- final elementwise math (reference op order) ---
    int tv = target[((size_t)b * HH + i) * WW + j];   // uncoalesced, L2-fed
    if (tv == 255) tv = tmin;
    float gtv = (float)tv;
    float pcv = pc ? 1.0f : 0.0f;
    float err  = fabsf(gtv - pcv);
    float dist = sqrtf(pd * pd + gd * gd);
    float mult = sqrtf(err * dist + 1e-9f);

    __shared__ float red[HH];
    red[i] = mult;
    __syncthreads();
    for (int st = 128; st > 0; st >>= 1) {
        if (i < st) red[i] += red[i + st];
        __syncthreads();
    }
    if (i == 0) partials[blk] = red[0];
}

// ---------------------------------------------------------------------------
// K3: final deterministic reduction of B*W partials -> mean (fixed order)
__global__ void k_final(const float* __restrict__ partials, float* __restrict__ out) {
    __shared__ float s[256];
    float acc = 0.0f;
    for (int k = threadIdx.x; k < BB * WW; k += 256) acc += partials[k];
    s[threadIdx.x] = acc;
    __syncthreads();
    for (int st = 128; st > 0; st >>= 1) {
        if (threadIdx.x < st) s[threadIdx.x] += s[threadIdx.x + st];
        __syncthreads();
    }
    if (threadIdx.x == 0) out[0] = s[0] * (1.0f / (float)NPIX);  // /2^19: exact
}

// ---------------------------------------------------------------------------
extern "C" void kernel_launch(void* const* d_in, const int* in_sizes, int n_in,
                              void* d_out, int out_size, void* d_ws, size_t ws_size,
                              hipStream_t stream) {
    const float* preds  = (const float*)d_in[0];
    const int*   target = (const int*)d_in[1];
    float* out = (float*)d_out;

    // ws layout: 3 mask arrays (64 KB each), partials, tmin partials
    ull* mPC   = (ull*)d_ws;                         // 8*256*4 ULL
    ull* mGT0  = mPC  + (size_t)BB * HH * 4;
    ull* mG255 = mGT0 + (size_t)BB * HH * 4;
    float* partials = (float*)(mG255 + (size_t)BB * HH * 4);   // B*W floats
    int*   tminPart = (int*)(partials + BB * WW);              // 256 ints

    k_masks<<<256, 256, 0, stream>>>(preds, target, mPC, mGT0, mG255, tminPart);
    k_fused<<<BB * WW, HH, 0, stream>>>(target, mPC, mGT0, mG255, tminPart, partials);
    k_final<<<1, 256, 0, stream>>>(partials, out);
}